// Round 10
// baseline (129.680 us; speedup 1.0000x reference)
//
#include <hip/hip_runtime.h>

typedef __attribute__((ext_vector_type(8))) _Float16 f16x8;
typedef __attribute__((ext_vector_type(4))) _Float16 f16x4;
typedef __attribute__((ext_vector_type(2))) __fp16 fp16x2;
typedef __attribute__((ext_vector_type(4))) float f32x4;

union U4 { f16x4 v; fp16x2 p[2]; };

__device__ __forceinline__ f16x4 cvt4(f32x4 a) {
  U4 u;
  u.p[0] = __builtin_amdgcn_cvt_pkrtz(a.x, a.y);
  u.p[1] = __builtin_amdgcn_cvt_pkrtz(a.z, a.w);
  return u.v;
}
__device__ __forceinline__ float dot4(f32x4 a, f32x4 b) {
  return a.x * b.x + a.y * b.y + a.z * b.z + a.w * b.w;
}

// K=32 zero-shuffle B<->C chaining via k-permutation:
//   A-frag k-position (kt, q, j) holds W column F = 32kt + 16*(j>=4) + 4q + (j&3),
//   so the B operand = concat(C_frag[nt=2kt], C_frag[nt=2kt+1]) -- lane-local.
// W staged in LDS in fragment order (lane-contiguous b128 reads, conflict-free).
// Aggregate-before-matmul in f16 C-frag space (1x FLOPs). One barrier total.
// LDS lane-dim padded 64->80: pushes LDS to 41 KB -> 3 blocks/CU occupancy
// target -> compiler register budget 170 (r9: 36KB -> 4-block target -> 128-reg
// clamp -> 114 MB scratch spill. Do not shrink the pad.)
__global__ __launch_bounds__(256, 2) void gcn_fused(
    const float* __restrict__ x,
    const float* __restrict__ W1, const float* __restrict__ B1,
    const float* __restrict__ W2, const float* __restrict__ B2,
    const float* __restrict__ W3, const float* __restrict__ B3,
    const float* __restrict__ W4, const float* __restrict__ B4,
    const float* __restrict__ fcw, const float* __restrict__ fcb,
    float* __restrict__ out)
{
  __shared__ __align__(16) _Float16 wlds[4][4][2][80][8];  // [l][nt][kt][lane(pad)][8]
  __shared__ float blds[4][64];

  const int tid  = threadIdx.x;
  const int lane = tid & 63;
  const int c    = lane & 15;   // A-row local / C col (batch)
  const int q    = lane >> 4;   // k-group / C row-group
  const int w    = tid >> 6;
  const int b    = blockIdx.x * 64 + w * 16 + c;  // this lane's batch row

  const float* Wg[4]  = {W1, W2, W3, W4};
  const float* Bgp[4] = {B1, B2, B3, B4};
  const int NB0[6] = {1, 0, 1, 2, 3, 3};
  const int NB1[6] = {2, 2, 3, 4, 5, 4};

  // ---- stage cb_l*W_l into LDS in k-permuted fragment order ----
#pragma unroll
  for (int l = 0; l < 4; ++l) {
    const float s = (l < 2) ? (1.f / 3.f) : 0.25f;
#pragma unroll
    for (int rep = 0; rep < 4; ++rep) {
      const int idx = rep * 1024 + tid * 4;       // flat f32 idx in 64x64 W_l
      const int row = idx >> 6, col = idx & 63;   // out-feat row, in-feat col
      const int nt = row >> 4, ca = row & 15;
      const int kt = col >> 5, ss = (col >> 4) & 1, qq = (col >> 2) & 3;
      f32x4 v = *(const f32x4*)(Wg[l] + idx);
      v *= s;
      *(f16x4*)&wlds[l][nt][kt][qq * 16 + ca][ss * 4] = cvt4(v);
    }
  }
  blds[w][lane] = Bgp[w][lane];   // 4 waves x 64 lanes = all biases

  // ---- x -> hC (C-frag-order f16 regs) + residual fc-dot q-partials ----
  f16x4 hC[6][4];   // [node][m]: lane (c,q) holds feats m*16+4q+{0..3} of batch b
  float pacc[6];
  {
    const float* xr = x + (size_t)b * 384 + q * 4;
#pragma unroll
    for (int n = 0; n < 6; ++n) {
      float p = 0.f;
#pragma unroll
      for (int m = 0; m < 4; ++m) {
        f32x4 v  = *(const f32x4*)(xr + n * 64 + m * 16);
        f32x4 fw = *(const f32x4*)(fcw + n * 64 + m * 16 + q * 4);
        p += dot4(v, fw);
        hC[n][m] = cvt4(v);
      }
      pacc[n] = p;
    }
  }
  __syncthreads();  // staging visible; only barrier in the kernel

  float sv[6];
#pragma unroll
  for (int l = 0; l < 4; ++l) {
    // aggregate in f16 C-frag space (identical layouts across nodes); hC dies here
    f16x8 ag[6][2];
#pragma unroll
    for (int n = 0; n < 6; ++n)
#pragma unroll
      for (int kt = 0; kt < 2; ++kt) {
        f16x4 lo = hC[n][2 * kt]     + hC[NB0[n]][2 * kt]     + hC[NB1[n]][2 * kt];
        f16x4 hi = hC[n][2 * kt + 1] + hC[NB0[n]][2 * kt + 1] + hC[NB1[n]][2 * kt + 1];
        if (l >= 2) { lo = lo + hC[n][2 * kt]; hi = hi + hC[n][2 * kt + 1]; }  // ca=2cb
        ag[n][kt] = __builtin_shufflevector(lo, hi, 0, 1, 2, 3, 4, 5, 6, 7);
      }
    if (l == 3) {
#pragma unroll
      for (int n = 0; n < 6; ++n) sv[n] = pacc[n];
    }
#pragma unroll
    for (int nt = 0; nt < 4; ++nt) {
      const f16x8 wf0  = *(const f16x8*)&wlds[l][nt][0][lane][0];
      const f16x8 wf1  = *(const f16x8*)&wlds[l][nt][1][lane][0];
      const f32x4 bias = *(const f32x4*)&blds[l][nt * 16 + q * 4];
#pragma unroll
      for (int n = 0; n < 6; ++n) {
        f32x4 acc = __builtin_amdgcn_mfma_f32_16x16x32_f16(wf0, ag[n][0], bias, 0, 0, 0);
        acc = __builtin_amdgcn_mfma_f32_16x16x32_f16(wf1, ag[n][1], acc, 0, 0, 0);
        if (l < 3) {
          f32x4 r;
#pragma unroll
          for (int e = 0; e < 4; ++e) r[e] = fmaxf(acc[e], 0.f);
          hC[n][nt] = cvt4(r);   // C-frag IS the next layer's B half-frag
        } else {
          f32x4 fw = *(const f32x4*)(fcw + n * 64 + nt * 16 + q * 4);
#pragma unroll
          for (int e = 0; e < 4; ++e) sv[n] += fmaxf(acc[e], 0.f) * fw[e];
        }
      }
    }
  }

  // ---- epilogue: reduce fc-dot over q-groups, sigmoid, store ----
#pragma unroll
  for (int n = 0; n < 6; ++n) {
    float t = sv[n];
    t += __shfl_xor(t, 16, 64);
    t += __shfl_xor(t, 32, 64);
    if (q == 0) {
      const float vz = t + fcb[n];
      out[(size_t)b * 6 + n] = 1.f / (1.f + __expf(-vz));
    }
  }
}

extern "C" void kernel_launch(void* const* d_in, const int* in_sizes, int n_in,
                              void* d_out, int out_size, void* d_ws, size_t ws_size,
                              hipStream_t stream) {
  const float* x   = (const float*)d_in[0];
  const float* W1  = (const float*)d_in[1];
  const float* B1  = (const float*)d_in[2];
  const float* W2  = (const float*)d_in[3];
  const float* B2  = (const float*)d_in[4];
  const float* W3  = (const float*)d_in[5];
  const float* B3  = (const float*)d_in[6];
  const float* W4  = (const float*)d_in[7];
  const float* B4  = (const float*)d_in[8];
  const float* fcw = (const float*)d_in[9];
  const float* fcb = (const float*)d_in[10];
  float* out = (float*)d_out;

  const int batch  = in_sizes[0] / 384;   // 131072
  const int blocks = batch / 64;          // 4 waves x 16 batch rows per block
  hipLaunchKernelGGL(gcn_fused, dim3(blocks), dim3(256), 0, stream,
                     x, W1, B1, W2, B2, W3, B3, W4, B4, fcw, fcb, out);
}